// Round 9
// baseline (1080.223 us; speedup 1.0000x reference)
//
#include <hip/hip_runtime.h>

#define K3 27
#define CENTER 13
#define NC 32
#define NREP 32   // histogram replicas (replica-major planes)

// ---------------------------------------------------------------------------
// gather one 32-float row into 8 float4 regs (zero if j < 0)
// ---------------------------------------------------------------------------
__device__ __forceinline__ void gather_row(float4* dst, const float* __restrict__ xF, int j)
{
    if (j >= 0) {
        const float4* src = (const float4*)(xF + (size_t)j * NC);
#pragma unroll
        for (int m = 0; m < 8; m++) dst[m] = src[m];
    } else {
        const float4 z = make_float4(0.f, 0.f, 0.f, 0.f);
#pragma unroll
        for (int m = 0; m < 8; m++) dst[m] = z;
    }
}

// acc[0..31] += g_row · W_k ; W uniform across lanes -> scalar (s_load) reads
__device__ __forceinline__ void tap_fma(float* acc, const float4* g, const float* __restrict__ Wk)
{
#pragma unroll
    for (int c8 = 0; c8 < 8; c8++) {
        const float4 gv = g[c8];
        const float* wb = Wk + (c8 * 4) * NC;
#pragma unroll
        for (int q = 0; q < 4; q++) {
            const float gc = (q == 0) ? gv.x : (q == 1) ? gv.y : (q == 2) ? gv.z : gv.w;
            const float4* wr = (const float4*)(wb + q * NC);
#pragma unroll
            for (int d4 = 0; d4 < 8; d4++) {
                const float4 w = wr[d4];
                acc[d4 * 4 + 0] = fmaf(gc, w.x, acc[d4 * 4 + 0]);
                acc[d4 * 4 + 1] = fmaf(gc, w.y, acc[d4 * 4 + 1]);
                acc[d4 * 4 + 2] = fmaf(gc, w.z, acc[d4 * 4 + 2]);
                acc[d4 * 4 + 3] = fmaf(gc, w.w, acc[d4 * 4 + 3]);
            }
        }
    }
}

// ---------------------------------------------------------------------------
// conv1: thread owns ONE point, all 32 out-channels. No LDS, no barriers.
// Gather double-buffered in regs (A/B); W streams via scalar loads.
// emits x row, s[n]=sum_d x (double), cn[n]=sum_d x^2 (double).
// ---------------------------------------------------------------------------
__global__ __launch_bounds__(256, 4) void conv1_kernel(
    const float* __restrict__ xF,
    const float* __restrict__ Wch,
    const float* __restrict__ bch,
    const int*   __restrict__ nbr,
    float*  __restrict__ xo,
    double* __restrict__ so,
    double* __restrict__ cno)
{
    const int n = blockIdx.x * 256 + threadIdx.x;
    const int* __restrict__ nrow = nbr + (size_t)n * K3;

    float acc[NC];
#pragma unroll
    for (int d = 0; d < NC; d++) acc[d] = 0.f;

    float4 A[8], B[8];
    gather_row(A, xF, nrow[0]);

#pragma unroll 1
    for (int kk = 0; kk < 26; kk += 2) {
        gather_row(B, xF, nrow[kk + 1]);          // in flight under tap kk
        tap_fma(acc, A, Wch + kk * (NC * NC));
        gather_row(A, xF, nrow[kk + 2]);          // in flight under tap kk+1
        tap_fma(acc, B, Wch + (kk + 1) * (NC * NC));
    }
    tap_fma(acc, A, Wch + 26 * (NC * NC));

    // bias + reductions (double, same order as prior rounds) + writeout
    double sum = 0.0, sq = 0.0;
    float4* xr = (float4*)(xo + (size_t)n * NC);
#pragma unroll
    for (int d4 = 0; d4 < 8; d4++) {
        const float4 bv = ((const float4*)bch)[d4];
        float4 v;
        v.x = acc[d4 * 4 + 0] + bv.x;
        v.y = acc[d4 * 4 + 1] + bv.y;
        v.z = acc[d4 * 4 + 2] + bv.z;
        v.w = acc[d4 * 4 + 3] + bv.w;
        sum += (double)v.x + (double)v.y + (double)v.z + (double)v.w;
        sq  += (double)v.x * v.x + (double)v.y * v.y + (double)v.z * v.z + (double)v.w * v.w;
        xr[d4] = v;
    }
    so[n]  = sum;
    cno[n] = sq;
}

// ---------------------------------------------------------------------------
// corr + replicated high-16 histogram, REPLICA-MAJOR: rep[r][batch][bin].
// ---------------------------------------------------------------------------
__global__ __launch_bounds__(256) void corr_hist_kernel(
    const double* __restrict__ s,
    const double* __restrict__ cn,
    const int*    __restrict__ nbr,
    unsigned*     __restrict__ key,
    unsigned*     __restrict__ rep,
    int NBpts, int N)
{
    __shared__ int nlds[256 * K3];
    const int t     = threadIdx.x;
    const int pbase = blockIdx.x * 256;
    {
        const int* g = nbr + (size_t)pbase * K3;
#pragma unroll
        for (int i = 0; i < K3; i++) nlds[i * 256 + t] = g[i * 256 + t];
    }
    __syncthreads();
    const int n = pbase + t;

    int jj[K3];
#pragma unroll
    for (int k = 0; k < K3; k++) jj[k] = nlds[t * K3 + k];

    double v[K3];
#pragma unroll
    for (int k = 0; k < K3; k++) {
        if (k == CENTER) continue;
        const int j  = jj[k];
        const int ja = (j < 0) ? 0 : j;
        const double val = s[ja];
        v[k] = (j < 0) ? 0.0 : val;
    }
    double a0 = 0.0, a1 = 0.0, a2 = 0.0, a3 = 0.0;
#pragma unroll
    for (int k = 0; k < K3; k++) {
        if (k == CENTER) continue;
        const int c = k & 3;
        if (c == 0) a0 += v[k];
        else if (c == 1) a1 += v[k];
        else if (c == 2) a2 += v[k];
        else a3 += v[k];
    }
    const double sum = (a0 + a1) + (a2 + a3);

    const float corr = (float)(sum / cn[n]);
    const unsigned uu = __float_as_uint(corr);
    const unsigned u  = (uu & 0x80000000u) ? ~uu : (uu | 0x80000000u);
    key[n] = u;
    const int b = n / NBpts;
    const unsigned r = (unsigned)blockIdx.x & (NREP - 1);
    atomicAdd(&rep[(size_t)r * (2u * 65536u) + (size_t)b * 65536u + (u >> 16)], 1u);
}

// ---------------------------------------------------------------------------
__global__ __launch_bounds__(256) void reduce_rep_kernel(
    const unsigned* __restrict__ rep,
    unsigned*       __restrict__ hist_sum)
{
    const int g = blockIdx.x * 256 + threadIdx.x;
    unsigned sum = 0;
#pragma unroll
    for (int r = 0; r < NREP; r++)
        sum += rep[(size_t)r * (2u * 65536u) + g];
    hist_sum[g] = sum;
}

// ---------------------------------------------------------------------------
__global__ __launch_bounds__(1024) void scan_hi_kernel(
    const unsigned* __restrict__ hist,
    const int*      __restrict__ thp,
    unsigned*       __restrict__ selhi,
    int*            __restrict__ selrk,
    int NBpts)
{
    __shared__ unsigned ss[1024];
    const int b = blockIdx.x;
    const int t = threadIdx.x;
    const unsigned* h = hist + (size_t)b * 65536u + t * 64;
    unsigned sum = 0;
#pragma unroll 8
    for (int i = 0; i < 64; i++) sum += h[i];
    ss[t] = sum;
    __syncthreads();
    for (int off = 1; off < 1024; off <<= 1) {
        unsigned v = (t + off < 1024) ? ss[t + off] : 0u;
        __syncthreads();
        ss[t] += v;
        __syncthreads();
    }
    int k = (int)((double)NBpts * (double)thp[0] / 3.21);
    if (k < 1) k = 1;
    if (k > NBpts) k = NBpts;
    unsigned run = ss[t] - sum;
    for (int i = 63; i >= 0; --i) {
        const unsigned c = h[i];
        if ((int)run < k && k <= (int)(run + c)) {
            selhi[b] = (unsigned)(t * 64 + i);
            selrk[b] = k - (int)run;
        }
        run += c;
    }
}

// ---------------------------------------------------------------------------
__global__ __launch_bounds__(256) void hist_lo_kernel(
    const unsigned* __restrict__ key,
    const unsigned* __restrict__ selhi,
    unsigned*       __restrict__ hist2,
    int NBpts, int N)
{
    const int n = blockIdx.x * 256 + threadIdx.x;
    if (n >= N) return;
    const int b = n / NBpts;
    const unsigned u = key[n];
    if ((u >> 16) == selhi[b])
        atomicAdd(&hist2[(size_t)b * 65536u + (u & 0xFFFFu)], 1u);
}

// ---------------------------------------------------------------------------
__global__ __launch_bounds__(1024) void scan_lo_kernel(
    const unsigned* __restrict__ hist2,
    const unsigned* __restrict__ selhi,
    const int*      __restrict__ selrk,
    unsigned*       __restrict__ selT,
    int*            __restrict__ selr)
{
    __shared__ unsigned ss[1024];
    const int b = blockIdx.x;
    const int t = threadIdx.x;
    const unsigned* h = hist2 + (size_t)b * 65536u + t * 64;
    unsigned sum = 0;
#pragma unroll 8
    for (int i = 0; i < 64; i++) sum += h[i];
    ss[t] = sum;
    __syncthreads();
    for (int off = 1; off < 1024; off <<= 1) {
        unsigned v = (t + off < 1024) ? ss[t + off] : 0u;
        __syncthreads();
        ss[t] += v;
        __syncthreads();
    }
    const int k = selrk[b];
    unsigned run = ss[t] - sum;
    for (int i = 63; i >= 0; --i) {
        const unsigned c = h[i];
        if ((int)run < k && k <= (int)(run + c)) {
            selT[b] = (selhi[b] << 16) | (unsigned)(t * 64 + i);
            selr[b] = k - (int)run;
        }
        run += c;
    }
}

// ---------------------------------------------------------------------------
__global__ __launch_bounds__(256) void mask_kernel(
    const unsigned* __restrict__ key,
    const unsigned* __restrict__ selT,
    int* __restrict__ mask,
    int* __restrict__ eqcnt,
    int NBpts)
{
    __shared__ int wc[4];
    const int n = blockIdx.x * 256 + threadIdx.x;
    const int b = n / NBpts;
    const unsigned u = key[n];
    const unsigned T = selT[b];
    mask[n] = (u > T) ? 1 : 0;
    const unsigned long long bal = __ballot(u == T);
    const int lane = threadIdx.x & 63;
    const int wid  = threadIdx.x >> 6;
    if (lane == 0) wc[wid] = __popcll(bal);
    __syncthreads();
    if (threadIdx.x == 0) eqcnt[blockIdx.x] = wc[0] + wc[1] + wc[2] + wc[3];
}

__global__ __launch_bounds__(512) void scan_kernel(
    const int* __restrict__ in, int* __restrict__ out,
    int n, int seg, int* __restrict__ total)
{
    __shared__ int ss[512];
    const int t = threadIdx.x;
    const int v = (t < n) ? in[t] : 0;
    ss[t] = v;
    __syncthreads();
    for (int off = 1; off < seg; off <<= 1) {
        int a = ((t & (seg - 1)) >= off) ? ss[t - off] : 0;
        __syncthreads();
        ss[t] += a;
        __syncthreads();
    }
    if (t < n) out[t] = ss[t] - v;
    if (total != nullptr && t == n - 1) total[0] = ss[t];
}

__global__ __launch_bounds__(256) void eqfinal_kernel(
    const unsigned* __restrict__ key,
    const unsigned* __restrict__ selT,
    const int*      __restrict__ selr,
    const int*      __restrict__ eqoff,
    int* __restrict__ mask,
    int* __restrict__ mcnt,
    int NBpts)
{
    __shared__ int wc[4], wm[4];
    const int n = blockIdx.x * 256 + threadIdx.x;
    const int b = n / NBpts;
    const unsigned u = key[n];
    const unsigned T = selT[b];
    const bool gt = (u > T);
    const bool eq = (u == T);
    const unsigned long long bal = __ballot(eq);
    const int lane = threadIdx.x & 63;
    const int wid  = threadIdx.x >> 6;
    if (lane == 0) wc[wid] = __popcll(bal);
    __syncthreads();
    int base = eqoff[blockIdx.x];
    for (int w = 0; w < wid; w++) base += wc[w];
    bool keep = false;
    if (eq) {
        const int g = base + __popcll(bal & ((1ull << lane) - 1ull));
        keep = (g < selr[b]);
        if (keep) mask[n] = 1;
    }
    const unsigned long long balm = __ballot(gt || keep);
    if (lane == 0) wm[wid] = __popcll(balm);
    __syncthreads();
    if (threadIdx.x == 0) mcnt[blockIdx.x] = wm[0] + wm[1] + wm[2] + wm[3];
}

__global__ __launch_bounds__(256) void emit_kernel(
    const int* __restrict__ mask,
    const int* __restrict__ moff,
    int* __restrict__ list)
{
    __shared__ int wc[4];
    const int n = blockIdx.x * 256 + threadIdx.x;
    const bool m = mask[n] != 0;
    const unsigned long long bal = __ballot(m);
    const int lane = threadIdx.x & 63;
    const int wid  = threadIdx.x >> 6;
    if (lane == 0) wc[wid] = __popcll(bal);
    __syncthreads();
    int base = moff[blockIdx.x];
    for (int w = 0; w < wid; w++) base += wc[w];
    if (m) list[base + __popcll(bal & ((1ull << lane) - 1ull))] = n;
}

// ---------------------------------------------------------------------------
__global__ __launch_bounds__(256) void scale2_kernel(
    const float4* __restrict__ x, float4* __restrict__ out, int n4)
{
    const int i = blockIdx.x * 256 + threadIdx.x;
    if (i < n4) {
        const float4 v = x[i];
        out[i] = make_float4(v.x + v.x, v.y + v.y, v.z + v.z, v.w + v.w);
    }
}

// ---------------------------------------------------------------------------
// conv2: thread owns one masked point (ordered list). No LDS, no barriers.
// ---------------------------------------------------------------------------
__device__ __forceinline__ void gather_row_m(float4* dst, const float* __restrict__ x,
                                             const int* __restrict__ mask, int j)
{
    const bool v = (j >= 0) && (mask[j] != 0);
    if (v) {
        const float4* src = (const float4*)(x + (size_t)j * NC);
#pragma unroll
        for (int m = 0; m < 8; m++) dst[m] = src[m];
    } else {
        const float4 z = make_float4(0.f, 0.f, 0.f, 0.f);
#pragma unroll
        for (int m = 0; m < 8; m++) dst[m] = z;
    }
}

__global__ __launch_bounds__(256, 4) void conv2_kernel(
    const float* __restrict__ x,
    const float* __restrict__ Wdw,
    const float* __restrict__ bdw,
    const int*   __restrict__ nbr,
    const int*   __restrict__ mask,
    const int*   __restrict__ list,
    const int*   __restrict__ cnt,
    float* __restrict__ out)
{
    const int count = *cnt;
    const int base  = blockIdx.x << 8;
    if (base >= count) return;              // block-uniform early exit
    const int idx = base + threadIdx.x;
    const int myp = (idx < count) ? list[idx] : -1;
    const int* __restrict__ nrow = nbr + (size_t)((myp >= 0) ? myp : 0) * K3;

    float acc[NC];
#pragma unroll
    for (int d = 0; d < NC; d++) acc[d] = 0.f;

    float4 A[8], B[8];
    gather_row_m(A, x, mask, (myp >= 0) ? nrow[0] : -1);

#pragma unroll 1
    for (int kk = 0; kk < 26; kk += 2) {
        gather_row_m(B, x, mask, (myp >= 0) ? nrow[kk + 1] : -1);
        tap_fma(acc, A, Wdw + kk * (NC * NC));
        gather_row_m(A, x, mask, (myp >= 0) ? nrow[kk + 2] : -1);
        tap_fma(acc, B, Wdw + (kk + 1) * (NC * NC));
    }
    tap_fma(acc, A, Wdw + 26 * (NC * NC));

    if (myp >= 0) {
        const float4* xr = (const float4*)(x + (size_t)myp * NC);
        float4* orow = (float4*)(out + (size_t)myp * NC);
#pragma unroll
        for (int d4 = 0; d4 < 8; d4++) {
            const float4 bv = ((const float4*)bdw)[d4];
            const float4 xv = xr[d4];
            float4 v;
            v.x = (acc[d4 * 4 + 0] + bv.x) + xv.x;
            v.y = (acc[d4 * 4 + 1] + bv.y) + xv.y;
            v.z = (acc[d4 * 4 + 2] + bv.z) + xv.z;
            v.w = (acc[d4 * 4 + 3] + bv.w) + xv.w;
            orow[d4] = v;
        }
    }
}

// ---------------------------------------------------------------------------
extern "C" void kernel_launch(void* const* d_in, const int* in_sizes, int n_in,
                              void* d_out, int out_size, void* d_ws, size_t ws_size,
                              hipStream_t stream)
{
    const float* xF  = (const float*)d_in[0];
    const float* Wch = (const float*)d_in[1];
    const float* bch = (const float*)d_in[2];
    const float* Wdw = (const float*)d_in[3];
    const float* bdw = (const float*)d_in[4];
    const int*   nbr = (const int*)d_in[5];
    const int*   thp = (const int*)d_in[6];

    const int N = in_sizes[0] / NC;   // 131072
    const int NBpts = N / 2;          // 65536 per batch
    float* out = (float*)d_out;

    char* ws = (char*)d_ws;
    size_t off = 0;
    float*    x     = (float*)(ws + off);    off += (size_t)N * NC * sizeof(float);
    double*   s     = (double*)(ws + off);   off += (size_t)N * sizeof(double);
    double*   cn    = (double*)(ws + off);   off += (size_t)N * sizeof(double);
    unsigned* key   = (unsigned*)(ws + off); off += (size_t)N * sizeof(unsigned);
    int*      mask  = (int*)(ws + off);      off += (size_t)N * sizeof(int);
    int*      list  = (int*)(ws + off);      off += (size_t)N * sizeof(int);
    unsigned* hsum  = (unsigned*)(ws + off); off += 2u * 65536u * sizeof(unsigned);
    unsigned* hist2 = (unsigned*)(ws + off); off += 2u * 65536u * sizeof(unsigned);
    const size_t zero_bytes = 2u * 65536u * sizeof(unsigned);
    int*      cnt   = (int*)(ws + off);      off += 256;
    unsigned* selhi = (unsigned*)(ws + off); off += 256;
    int*      selrk = (int*)(ws + off);      off += 256;
    unsigned* selT  = (unsigned*)(ws + off); off += 256;
    int*      selr  = (int*)(ws + off);      off += 256;
    int*      eqcnt = (int*)(ws + off);      off += 512 * sizeof(int);
    int*      eqoff = (int*)(ws + off);      off += 512 * sizeof(int);
    int*      mcnt  = (int*)(ws + off);      off += 512 * sizeof(int);
    int*      moff  = (int*)(ws + off);      off += 512 * sizeof(int);

    const int nblk = N / 256;  // 512

    // d_out doubles as the replica-major histogram scratch; scale2 overwrites.
    unsigned* rep = (unsigned*)d_out;

    hipMemsetAsync(rep, 0, (size_t)out_size * sizeof(float), stream);
    hipMemsetAsync(hist2, 0, zero_bytes, stream);
    conv1_kernel<<<nblk, 256, 0, stream>>>(xF, Wch, bch, nbr, x, s, cn);
    corr_hist_kernel<<<nblk, 256, 0, stream>>>(s, cn, nbr, key, rep, NBpts, N);
    reduce_rep_kernel<<<nblk, 256, 0, stream>>>(rep, hsum);
    scan_hi_kernel<<<2, 1024, 0, stream>>>(hsum, thp, selhi, selrk, NBpts);
    hist_lo_kernel<<<nblk, 256, 0, stream>>>(key, selhi, hist2, NBpts, N);
    scan_lo_kernel<<<2, 1024, 0, stream>>>(hist2, selhi, selrk, selT, selr);
    mask_kernel<<<nblk, 256, 0, stream>>>(key, selT, mask, eqcnt, NBpts);
    scan_kernel<<<1, 512, 0, stream>>>(eqcnt, eqoff, nblk, 256, nullptr);
    eqfinal_kernel<<<nblk, 256, 0, stream>>>(key, selT, selr, eqoff, mask, mcnt, NBpts);
    scan_kernel<<<1, 512, 0, stream>>>(mcnt, moff, nblk, 512, cnt);
    emit_kernel<<<nblk, 256, 0, stream>>>(mask, moff, list);
    scale2_kernel<<<(N * NC / 4) / 256, 256, 0, stream>>>((const float4*)x, (float4*)out, N * NC / 4);
    conv2_kernel<<<nblk, 256, 0, stream>>>(x, Wdw, bdw, nbr, mask, list, cnt, out);
}

// Round 10
// 841.995 us; speedup vs baseline: 1.2829x; 1.2829x over previous
//
#include <hip/hip_runtime.h>

#define K3 27
#define CENTER 13
#define NC 32
#define NREP 32   // histogram replicas (replica-major planes)

// ---------------------------------------------------------------------------
// gather one 32-float row into 8 float4 regs (zero if j < 0)
// ---------------------------------------------------------------------------
__device__ __forceinline__ void gather_row(float4* dst, const float* __restrict__ xF, int j)
{
    if (j >= 0) {
        const float4* src = (const float4*)(xF + (size_t)j * NC);
#pragma unroll
        for (int m = 0; m < 8; m++) dst[m] = src[m];
    } else {
        const float4 z = make_float4(0.f, 0.f, 0.f, 0.f);
#pragma unroll
        for (int m = 0; m < 8; m++) dst[m] = z;
    }
}

// acc[0..31] += g_row · W_k ; W uniform across lanes -> scalar (s_load) reads
__device__ __forceinline__ void tap_fma(float* acc, const float4* g, const float* __restrict__ Wk)
{
#pragma unroll
    for (int c8 = 0; c8 < 8; c8++) {
        const float4 gv = g[c8];
        const float* wb = Wk + (c8 * 4) * NC;
#pragma unroll
        for (int q = 0; q < 4; q++) {
            const float gc = (q == 0) ? gv.x : (q == 1) ? gv.y : (q == 2) ? gv.z : gv.w;
            const float4* wr = (const float4*)(wb + q * NC);
#pragma unroll
            for (int d4 = 0; d4 < 8; d4++) {
                const float4 w = wr[d4];
                acc[d4 * 4 + 0] = fmaf(gc, w.x, acc[d4 * 4 + 0]);
                acc[d4 * 4 + 1] = fmaf(gc, w.y, acc[d4 * 4 + 1]);
                acc[d4 * 4 + 2] = fmaf(gc, w.z, acc[d4 * 4 + 2]);
                acc[d4 * 4 + 3] = fmaf(gc, w.w, acc[d4 * 4 + 3]);
            }
        }
    }
}

// ---------------------------------------------------------------------------
// conv1: thread owns ONE point, all 32 out-channels. No LDS, no barriers.
// Gather double-buffered in regs (A/B); W streams via scalar loads.
// __launch_bounds__(256,2): cap 128 VGPR — working set ~110, NO SPILL
// (R9's (256,4) capped at 64 VGPR -> 915 MB scratch writes, 5.5x regression).
// ---------------------------------------------------------------------------
__global__ __launch_bounds__(256, 2) void conv1_kernel(
    const float* __restrict__ xF,
    const float* __restrict__ Wch,
    const float* __restrict__ bch,
    const int*   __restrict__ nbr,
    float*  __restrict__ xo,
    double* __restrict__ so,
    double* __restrict__ cno)
{
    const int n = blockIdx.x * 256 + threadIdx.x;
    const int* __restrict__ nrow = nbr + (size_t)n * K3;

    float acc[NC];
#pragma unroll
    for (int d = 0; d < NC; d++) acc[d] = 0.f;

    float4 A[8], B[8];
    gather_row(A, xF, nrow[0]);

#pragma unroll 1
    for (int kk = 0; kk < 26; kk += 2) {
        gather_row(B, xF, nrow[kk + 1]);          // in flight under tap kk
        tap_fma(acc, A, Wch + kk * (NC * NC));
        gather_row(A, xF, nrow[kk + 2]);          // in flight under tap kk+1
        tap_fma(acc, B, Wch + (kk + 1) * (NC * NC));
    }
    tap_fma(acc, A, Wch + 26 * (NC * NC));

    // bias + reductions (double, same order as prior rounds) + writeout
    double sum = 0.0, sq = 0.0;
    float4* xr = (float4*)(xo + (size_t)n * NC);
#pragma unroll
    for (int d4 = 0; d4 < 8; d4++) {
        const float4 bv = ((const float4*)bch)[d4];
        float4 v;
        v.x = acc[d4 * 4 + 0] + bv.x;
        v.y = acc[d4 * 4 + 1] + bv.y;
        v.z = acc[d4 * 4 + 2] + bv.z;
        v.w = acc[d4 * 4 + 3] + bv.w;
        sum += (double)v.x + (double)v.y + (double)v.z + (double)v.w;
        sq  += (double)v.x * v.x + (double)v.y * v.y + (double)v.z * v.z + (double)v.w * v.w;
        xr[d4] = v;
    }
    so[n]  = sum;
    cno[n] = sq;
}

// ---------------------------------------------------------------------------
// corr + replicated high-16 histogram, REPLICA-MAJOR: rep[r][batch][bin].
// ---------------------------------------------------------------------------
__global__ __launch_bounds__(256) void corr_hist_kernel(
    const double* __restrict__ s,
    const double* __restrict__ cn,
    const int*    __restrict__ nbr,
    unsigned*     __restrict__ key,
    unsigned*     __restrict__ rep,
    int NBpts, int N)
{
    __shared__ int nlds[256 * K3];
    const int t     = threadIdx.x;
    const int pbase = blockIdx.x * 256;
    {
        const int* g = nbr + (size_t)pbase * K3;
#pragma unroll
        for (int i = 0; i < K3; i++) nlds[i * 256 + t] = g[i * 256 + t];
    }
    __syncthreads();
    const int n = pbase + t;

    int jj[K3];
#pragma unroll
    for (int k = 0; k < K3; k++) jj[k] = nlds[t * K3 + k];

    double v[K3];
#pragma unroll
    for (int k = 0; k < K3; k++) {
        if (k == CENTER) continue;
        const int j  = jj[k];
        const int ja = (j < 0) ? 0 : j;
        const double val = s[ja];
        v[k] = (j < 0) ? 0.0 : val;
    }
    double a0 = 0.0, a1 = 0.0, a2 = 0.0, a3 = 0.0;
#pragma unroll
    for (int k = 0; k < K3; k++) {
        if (k == CENTER) continue;
        const int c = k & 3;
        if (c == 0) a0 += v[k];
        else if (c == 1) a1 += v[k];
        else if (c == 2) a2 += v[k];
        else a3 += v[k];
    }
    const double sum = (a0 + a1) + (a2 + a3);

    const float corr = (float)(sum / cn[n]);
    const unsigned uu = __float_as_uint(corr);
    const unsigned u  = (uu & 0x80000000u) ? ~uu : (uu | 0x80000000u);
    key[n] = u;
    const int b = n / NBpts;
    const unsigned r = (unsigned)blockIdx.x & (NREP - 1);
    atomicAdd(&rep[(size_t)r * (2u * 65536u) + (size_t)b * 65536u + (u >> 16)], 1u);
}

// ---------------------------------------------------------------------------
__global__ __launch_bounds__(256) void reduce_rep_kernel(
    const unsigned* __restrict__ rep,
    unsigned*       __restrict__ hist_sum)
{
    const int g = blockIdx.x * 256 + threadIdx.x;
    unsigned sum = 0;
#pragma unroll
    for (int r = 0; r < NREP; r++)
        sum += rep[(size_t)r * (2u * 65536u) + g];
    hist_sum[g] = sum;
}

// ---------------------------------------------------------------------------
__global__ __launch_bounds__(1024) void scan_hi_kernel(
    const unsigned* __restrict__ hist,
    const int*      __restrict__ thp,
    unsigned*       __restrict__ selhi,
    int*            __restrict__ selrk,
    int NBpts)
{
    __shared__ unsigned ss[1024];
    const int b = blockIdx.x;
    const int t = threadIdx.x;
    const unsigned* h = hist + (size_t)b * 65536u + t * 64;
    unsigned sum = 0;
#pragma unroll 8
    for (int i = 0; i < 64; i++) sum += h[i];
    ss[t] = sum;
    __syncthreads();
    for (int off = 1; off < 1024; off <<= 1) {
        unsigned v = (t + off < 1024) ? ss[t + off] : 0u;
        __syncthreads();
        ss[t] += v;
        __syncthreads();
    }
    int k = (int)((double)NBpts * (double)thp[0] / 3.21);
    if (k < 1) k = 1;
    if (k > NBpts) k = NBpts;
    unsigned run = ss[t] - sum;
    for (int i = 63; i >= 0; --i) {
        const unsigned c = h[i];
        if ((int)run < k && k <= (int)(run + c)) {
            selhi[b] = (unsigned)(t * 64 + i);
            selrk[b] = k - (int)run;
        }
        run += c;
    }
}

// ---------------------------------------------------------------------------
__global__ __launch_bounds__(256) void hist_lo_kernel(
    const unsigned* __restrict__ key,
    const unsigned* __restrict__ selhi,
    unsigned*       __restrict__ hist2,
    int NBpts, int N)
{
    const int n = blockIdx.x * 256 + threadIdx.x;
    if (n >= N) return;
    const int b = n / NBpts;
    const unsigned u = key[n];
    if ((u >> 16) == selhi[b])
        atomicAdd(&hist2[(size_t)b * 65536u + (u & 0xFFFFu)], 1u);
}

// ---------------------------------------------------------------------------
__global__ __launch_bounds__(1024) void scan_lo_kernel(
    const unsigned* __restrict__ hist2,
    const unsigned* __restrict__ selhi,
    const int*      __restrict__ selrk,
    unsigned*       __restrict__ selT,
    int*            __restrict__ selr)
{
    __shared__ unsigned ss[1024];
    const int b = blockIdx.x;
    const int t = threadIdx.x;
    const unsigned* h = hist2 + (size_t)b * 65536u + t * 64;
    unsigned sum = 0;
#pragma unroll 8
    for (int i = 0; i < 64; i++) sum += h[i];
    ss[t] = sum;
    __syncthreads();
    for (int off = 1; off < 1024; off <<= 1) {
        unsigned v = (t + off < 1024) ? ss[t + off] : 0u;
        __syncthreads();
        ss[t] += v;
        __syncthreads();
    }
    const int k = selrk[b];
    unsigned run = ss[t] - sum;
    for (int i = 63; i >= 0; --i) {
        const unsigned c = h[i];
        if ((int)run < k && k <= (int)(run + c)) {
            selT[b] = (selhi[b] << 16) | (unsigned)(t * 64 + i);
            selr[b] = k - (int)run;
        }
        run += c;
    }
}

// ---------------------------------------------------------------------------
__global__ __launch_bounds__(256) void mask_kernel(
    const unsigned* __restrict__ key,
    const unsigned* __restrict__ selT,
    int* __restrict__ mask,
    int* __restrict__ eqcnt,
    int NBpts)
{
    __shared__ int wc[4];
    const int n = blockIdx.x * 256 + threadIdx.x;
    const int b = n / NBpts;
    const unsigned u = key[n];
    const unsigned T = selT[b];
    mask[n] = (u > T) ? 1 : 0;
    const unsigned long long bal = __ballot(u == T);
    const int lane = threadIdx.x & 63;
    const int wid  = threadIdx.x >> 6;
    if (lane == 0) wc[wid] = __popcll(bal);
    __syncthreads();
    if (threadIdx.x == 0) eqcnt[blockIdx.x] = wc[0] + wc[1] + wc[2] + wc[3];
}

__global__ __launch_bounds__(512) void scan_kernel(
    const int* __restrict__ in, int* __restrict__ out,
    int n, int seg, int* __restrict__ total)
{
    __shared__ int ss[512];
    const int t = threadIdx.x;
    const int v = (t < n) ? in[t] : 0;
    ss[t] = v;
    __syncthreads();
    for (int off = 1; off < seg; off <<= 1) {
        int a = ((t & (seg - 1)) >= off) ? ss[t - off] : 0;
        __syncthreads();
        ss[t] += a;
        __syncthreads();
    }
    if (t < n) out[t] = ss[t] - v;
    if (total != nullptr && t == n - 1) total[0] = ss[t];
}

__global__ __launch_bounds__(256) void eqfinal_kernel(
    const unsigned* __restrict__ key,
    const unsigned* __restrict__ selT,
    const int*      __restrict__ selr,
    const int*      __restrict__ eqoff,
    int* __restrict__ mask,
    int* __restrict__ mcnt,
    int NBpts)
{
    __shared__ int wc[4], wm[4];
    const int n = blockIdx.x * 256 + threadIdx.x;
    const int b = n / NBpts;
    const unsigned u = key[n];
    const unsigned T = selT[b];
    const bool gt = (u > T);
    const bool eq = (u == T);
    const unsigned long long bal = __ballot(eq);
    const int lane = threadIdx.x & 63;
    const int wid  = threadIdx.x >> 6;
    if (lane == 0) wc[wid] = __popcll(bal);
    __syncthreads();
    int base = eqoff[blockIdx.x];
    for (int w = 0; w < wid; w++) base += wc[w];
    bool keep = false;
    if (eq) {
        const int g = base + __popcll(bal & ((1ull << lane) - 1ull));
        keep = (g < selr[b]);
        if (keep) mask[n] = 1;
    }
    const unsigned long long balm = __ballot(gt || keep);
    if (lane == 0) wm[wid] = __popcll(balm);
    __syncthreads();
    if (threadIdx.x == 0) mcnt[blockIdx.x] = wm[0] + wm[1] + wm[2] + wm[3];
}

__global__ __launch_bounds__(256) void emit_kernel(
    const int* __restrict__ mask,
    const int* __restrict__ moff,
    int* __restrict__ list)
{
    __shared__ int wc[4];
    const int n = blockIdx.x * 256 + threadIdx.x;
    const bool m = mask[n] != 0;
    const unsigned long long bal = __ballot(m);
    const int lane = threadIdx.x & 63;
    const int wid  = threadIdx.x >> 6;
    if (lane == 0) wc[wid] = __popcll(bal);
    __syncthreads();
    int base = moff[blockIdx.x];
    for (int w = 0; w < wid; w++) base += wc[w];
    if (m) list[base + __popcll(bal & ((1ull << lane) - 1ull))] = n;
}

// ---------------------------------------------------------------------------
__global__ __launch_bounds__(256) void scale2_kernel(
    const float4* __restrict__ x, float4* __restrict__ out, int n4)
{
    const int i = blockIdx.x * 256 + threadIdx.x;
    if (i < n4) {
        const float4 v = x[i];
        out[i] = make_float4(v.x + v.x, v.y + v.y, v.z + v.z, v.w + v.w);
    }
}

// ---------------------------------------------------------------------------
// conv2: thread owns one masked point (ordered list). No LDS, no barriers.
// ---------------------------------------------------------------------------
__device__ __forceinline__ void gather_row_m(float4* dst, const float* __restrict__ x,
                                             const int* __restrict__ mask, int j)
{
    const bool v = (j >= 0) && (mask[j] != 0);
    if (v) {
        const float4* src = (const float4*)(x + (size_t)j * NC);
#pragma unroll
        for (int m = 0; m < 8; m++) dst[m] = src[m];
    } else {
        const float4 z = make_float4(0.f, 0.f, 0.f, 0.f);
#pragma unroll
        for (int m = 0; m < 8; m++) dst[m] = z;
    }
}

__global__ __launch_bounds__(256, 2) void conv2_kernel(
    const float* __restrict__ x,
    const float* __restrict__ Wdw,
    const float* __restrict__ bdw,
    const int*   __restrict__ nbr,
    const int*   __restrict__ mask,
    const int*   __restrict__ list,
    const int*   __restrict__ cnt,
    float* __restrict__ out)
{
    const int count = *cnt;
    const int base  = blockIdx.x << 8;
    if (base >= count) return;              // block-uniform early exit
    const int idx = base + threadIdx.x;
    const int myp = (idx < count) ? list[idx] : -1;
    const int* __restrict__ nrow = nbr + (size_t)((myp >= 0) ? myp : 0) * K3;

    float acc[NC];
#pragma unroll
    for (int d = 0; d < NC; d++) acc[d] = 0.f;

    float4 A[8], B[8];
    gather_row_m(A, x, mask, (myp >= 0) ? nrow[0] : -1);

#pragma unroll 1
    for (int kk = 0; kk < 26; kk += 2) {
        gather_row_m(B, x, mask, (myp >= 0) ? nrow[kk + 1] : -1);
        tap_fma(acc, A, Wdw + kk * (NC * NC));
        gather_row_m(A, x, mask, (myp >= 0) ? nrow[kk + 2] : -1);
        tap_fma(acc, B, Wdw + (kk + 1) * (NC * NC));
    }
    tap_fma(acc, A, Wdw + 26 * (NC * NC));

    if (myp >= 0) {
        const float4* xr = (const float4*)(x + (size_t)myp * NC);
        float4* orow = (float4*)(out + (size_t)myp * NC);
#pragma unroll
        for (int d4 = 0; d4 < 8; d4++) {
            const float4 bv = ((const float4*)bdw)[d4];
            const float4 xv = xr[d4];
            float4 v;
            v.x = (acc[d4 * 4 + 0] + bv.x) + xv.x;
            v.y = (acc[d4 * 4 + 1] + bv.y) + xv.y;
            v.z = (acc[d4 * 4 + 2] + bv.z) + xv.z;
            v.w = (acc[d4 * 4 + 3] + bv.w) + xv.w;
            orow[d4] = v;
        }
    }
}

// ---------------------------------------------------------------------------
extern "C" void kernel_launch(void* const* d_in, const int* in_sizes, int n_in,
                              void* d_out, int out_size, void* d_ws, size_t ws_size,
                              hipStream_t stream)
{
    const float* xF  = (const float*)d_in[0];
    const float* Wch = (const float*)d_in[1];
    const float* bch = (const float*)d_in[2];
    const float* Wdw = (const float*)d_in[3];
    const float* bdw = (const float*)d_in[4];
    const int*   nbr = (const int*)d_in[5];
    const int*   thp = (const int*)d_in[6];

    const int N = in_sizes[0] / NC;   // 131072
    const int NBpts = N / 2;          // 65536 per batch
    float* out = (float*)d_out;

    char* ws = (char*)d_ws;
    size_t off = 0;
    float*    x     = (float*)(ws + off);    off += (size_t)N * NC * sizeof(float);
    double*   s     = (double*)(ws + off);   off += (size_t)N * sizeof(double);
    double*   cn    = (double*)(ws + off);   off += (size_t)N * sizeof(double);
    unsigned* key   = (unsigned*)(ws + off); off += (size_t)N * sizeof(unsigned);
    int*      mask  = (int*)(ws + off);      off += (size_t)N * sizeof(int);
    int*      list  = (int*)(ws + off);      off += (size_t)N * sizeof(int);
    unsigned* hsum  = (unsigned*)(ws + off); off += 2u * 65536u * sizeof(unsigned);
    unsigned* hist2 = (unsigned*)(ws + off); off += 2u * 65536u * sizeof(unsigned);
    const size_t zero_bytes = 2u * 65536u * sizeof(unsigned);
    int*      cnt   = (int*)(ws + off);      off += 256;
    unsigned* selhi = (unsigned*)(ws + off); off += 256;
    int*      selrk = (int*)(ws + off);      off += 256;
    unsigned* selT  = (unsigned*)(ws + off); off += 256;
    int*      selr  = (int*)(ws + off);      off += 256;
    int*      eqcnt = (int*)(ws + off);      off += 512 * sizeof(int);
    int*      eqoff = (int*)(ws + off);      off += 512 * sizeof(int);
    int*      mcnt  = (int*)(ws + off);      off += 512 * sizeof(int);
    int*      moff  = (int*)(ws + off);      off += 512 * sizeof(int);

    const int nblk = N / 256;  // 512

    // d_out doubles as the replica-major histogram scratch; scale2 overwrites.
    unsigned* rep = (unsigned*)d_out;

    hipMemsetAsync(rep, 0, (size_t)out_size * sizeof(float), stream);
    hipMemsetAsync(hist2, 0, zero_bytes, stream);
    conv1_kernel<<<nblk, 256, 0, stream>>>(xF, Wch, bch, nbr, x, s, cn);
    corr_hist_kernel<<<nblk, 256, 0, stream>>>(s, cn, nbr, key, rep, NBpts, N);
    reduce_rep_kernel<<<nblk, 256, 0, stream>>>(rep, hsum);
    scan_hi_kernel<<<2, 1024, 0, stream>>>(hsum, thp, selhi, selrk, NBpts);
    hist_lo_kernel<<<nblk, 256, 0, stream>>>(key, selhi, hist2, NBpts, N);
    scan_lo_kernel<<<2, 1024, 0, stream>>>(hist2, selhi, selrk, selT, selr);
    mask_kernel<<<nblk, 256, 0, stream>>>(key, selT, mask, eqcnt, NBpts);
    scan_kernel<<<1, 512, 0, stream>>>(eqcnt, eqoff, nblk, 256, nullptr);
    eqfinal_kernel<<<nblk, 256, 0, stream>>>(key, selT, selr, eqoff, mask, mcnt, NBpts);
    scan_kernel<<<1, 512, 0, stream>>>(mcnt, moff, nblk, 512, cnt);
    emit_kernel<<<nblk, 256, 0, stream>>>(mask, moff, list);
    scale2_kernel<<<(N * NC / 4) / 256, 256, 0, stream>>>((const float4*)x, (float4*)out, N * NC / 4);
    conv2_kernel<<<nblk, 256, 0, stream>>>(x, Wdw, bdw, nbr, mask, list, cnt, out);
}

// Round 11
// 360.859 us; speedup vs baseline: 2.9935x; 2.3333x over previous
//
#include <hip/hip_runtime.h>

#define K3 27
#define CENTER 13
#define NC 32
#define NREP 32   // histogram replicas (replica-major planes)

// ---------------------------------------------------------------------------
// conv1: R8 LDS-tile structure, 128-point tile for occupancy.
// 256 threads / 128 points; thread: dg=t>>6 (8 out-ch), pp=t&63 -> points
// {pp, pp+64}. G tile double-buffered in LDS (2x16KB, XOR swizzle);
// W via wave-uniform pointer (scalar loads). Staging: 2 threads/row.
// ---------------------------------------------------------------------------
__global__ __launch_bounds__(256) void conv1_kernel(
    const float* __restrict__ xF,
    const float* __restrict__ Wch,
    const float* __restrict__ bch,
    const int*   __restrict__ nbr,
    float*  __restrict__ xo,
    double* __restrict__ so,
    double* __restrict__ cno)
{
    __shared__ float Gs[2][128 * 32];      // 2 x 16 KB
    const int t     = threadIdx.x;
    const int pbase = blockIdx.x << 7;     // 128 points/block
    const int dgu   = __builtin_amdgcn_readfirstlane(t >> 6);
    const int pp    = t & 63;
    const int sw    = pp & 7;
    const int srow  = t >> 1;              // staging row (2 threads/row)
    const int sh    = t & 1;               // staging half
    const int stsw  = srow & 7;

    float acc[2][8];
#pragma unroll
    for (int i = 0; i < 2; i++)
#pragma unroll
        for (int d = 0; d < 8; d++) acc[i][d] = 0.f;

    float4 stg[4];
    {
        const int j = nbr[(size_t)(pbase + srow) * K3];
        if (j >= 0) {
            const float4* src = (const float4*)(xF + (size_t)j * NC) + sh * 4;
#pragma unroll
            for (int m = 0; m < 4; m++) stg[m] = src[m];
        } else {
            const float4 z = make_float4(0.f, 0.f, 0.f, 0.f);
#pragma unroll
            for (int m = 0; m < 4; m++) stg[m] = z;
        }
    }

    for (int k = 0; k < K3; k++) {
        const int cur = k & 1;
        {
            float4* dst = (float4*)(Gs[cur] + srow * 32);
#pragma unroll
            for (int m = 0; m < 4; m++) dst[(4 * sh + m) ^ stsw] = stg[m];
        }
        __syncthreads();
        if (k + 1 < K3) {
            const int j = nbr[(size_t)(pbase + srow) * K3 + k + 1];
            if (j >= 0) {
                const float4* src = (const float4*)(xF + (size_t)j * NC) + sh * 4;
#pragma unroll
                for (int m = 0; m < 4; m++) stg[m] = src[m];
            } else {
                const float4 z = make_float4(0.f, 0.f, 0.f, 0.f);
#pragma unroll
                for (int m = 0; m < 4; m++) stg[m] = z;
            }
        }
        const float* __restrict__ Wk = Wch + k * (NC * NC) + dgu * 8;
#pragma unroll
        for (int cc = 0; cc < 8; ++cc) {
            const float4 g0 = ((const float4*)(Gs[cur] + (pp     ) * 32))[cc ^ sw];
            const float4 g1 = ((const float4*)(Gs[cur] + (pp + 64) * 32))[cc ^ sw];
#pragma unroll
            for (int c4 = 0; c4 < 4; c4++) {
                const float* wr = Wk + (cc * 4 + c4) * NC;
                const float4 wa = ((const float4*)wr)[0];
                const float4 wb = ((const float4*)wr)[1];
                const float wv[8] = {wa.x, wa.y, wa.z, wa.w, wb.x, wb.y, wb.z, wb.w};
                const float gv[2] = {(&g0.x)[c4], (&g1.x)[c4]};
#pragma unroll
                for (int i = 0; i < 2; i++)
#pragma unroll
                    for (int d = 0; d < 8; d++)
                        acc[i][d] = fmaf(gv[i], wv[d], acc[i][d]);
            }
        }
        __syncthreads();
    }

#pragma unroll
    for (int d = 0; d < 8; d++) {
        const float bv = bch[dgu * 8 + d];
#pragma unroll
        for (int i = 0; i < 2; i++) acc[i][d] += bv;
    }
#pragma unroll
    for (int i = 0; i < 2; i++) {
        const int p = pp + 64 * i;
        float4* dst = (float4*)(Gs[0] + p * 32);
        dst[(dgu * 2    ) ^ sw] = make_float4(acc[i][0], acc[i][1], acc[i][2], acc[i][3]);
        dst[(dgu * 2 + 1) ^ sw] = make_float4(acc[i][4], acc[i][5], acc[i][6], acc[i][7]);
    }
    __syncthreads();
    if (t < 128) {
        double sum = 0.0, sq = 0.0;
        const float4* row = (const float4*)(Gs[0] + t * 32);
        const int tsw = t & 7;
#pragma unroll
        for (int m = 0; m < 8; m++) {
            const float4 v = row[m ^ tsw];
            sum += (double)v.x + (double)v.y + (double)v.z + (double)v.w;
            sq  += (double)v.x * v.x + (double)v.y * v.y + (double)v.z * v.z + (double)v.w * v.w;
        }
        so[pbase + t]  = sum;
        cno[pbase + t] = sq;
    }
    {
        float4* xout = (float4*)(xo + (size_t)pbase * NC);
#pragma unroll
        for (int f = 0; f < 4; f++) {
            const int idx = f * 256 + t;
            const int row = idx >> 3;
            const int m   = idx & 7;
            xout[idx] = ((const float4*)(Gs[0] + row * 32))[m ^ (row & 7)];
        }
    }
}

// ---------------------------------------------------------------------------
// corr + replicated high-16 histogram, REPLICA-MAJOR: rep[r][batch][bin].
// ---------------------------------------------------------------------------
__global__ __launch_bounds__(256) void corr_hist_kernel(
    const double* __restrict__ s,
    const double* __restrict__ cn,
    const int*    __restrict__ nbr,
    unsigned*     __restrict__ key,
    unsigned*     __restrict__ rep,
    int NBpts, int N)
{
    __shared__ int nlds[256 * K3];
    const int t     = threadIdx.x;
    const int pbase = blockIdx.x * 256;
    {
        const int* g = nbr + (size_t)pbase * K3;
#pragma unroll
        for (int i = 0; i < K3; i++) nlds[i * 256 + t] = g[i * 256 + t];
    }
    __syncthreads();
    const int n = pbase + t;

    int jj[K3];
#pragma unroll
    for (int k = 0; k < K3; k++) jj[k] = nlds[t * K3 + k];

    double v[K3];
#pragma unroll
    for (int k = 0; k < K3; k++) {
        if (k == CENTER) continue;
        const int j  = jj[k];
        const int ja = (j < 0) ? 0 : j;
        const double val = s[ja];
        v[k] = (j < 0) ? 0.0 : val;
    }
    double a0 = 0.0, a1 = 0.0, a2 = 0.0, a3 = 0.0;
#pragma unroll
    for (int k = 0; k < K3; k++) {
        if (k == CENTER) continue;
        const int c = k & 3;
        if (c == 0) a0 += v[k];
        else if (c == 1) a1 += v[k];
        else if (c == 2) a2 += v[k];
        else a3 += v[k];
    }
    const double sum = (a0 + a1) + (a2 + a3);

    const float corr = (float)(sum / cn[n]);
    const unsigned uu = __float_as_uint(corr);
    const unsigned u  = (uu & 0x80000000u) ? ~uu : (uu | 0x80000000u);
    key[n] = u;
    const int b = n / NBpts;
    const unsigned r = (unsigned)blockIdx.x & (NREP - 1);
    atomicAdd(&rep[(size_t)r * (2u * 65536u) + (size_t)b * 65536u + (u >> 16)], 1u);
}

// ---------------------------------------------------------------------------
__global__ __launch_bounds__(256) void reduce_rep_kernel(
    const unsigned* __restrict__ rep,
    unsigned*       __restrict__ hist_sum)
{
    const int g = blockIdx.x * 256 + threadIdx.x;
    unsigned sum = 0;
#pragma unroll
    for (int r = 0; r < NREP; r++)
        sum += rep[(size_t)r * (2u * 65536u) + g];
    hist_sum[g] = sum;
}

// ---------------------------------------------------------------------------
__global__ __launch_bounds__(1024) void scan_hi_kernel(
    const unsigned* __restrict__ hist,
    const int*      __restrict__ thp,
    unsigned*       __restrict__ selhi,
    int*            __restrict__ selrk,
    int NBpts)
{
    __shared__ unsigned ss[1024];
    const int b = blockIdx.x;
    const int t = threadIdx.x;
    const unsigned* h = hist + (size_t)b * 65536u + t * 64;
    unsigned sum = 0;
#pragma unroll 8
    for (int i = 0; i < 64; i++) sum += h[i];
    ss[t] = sum;
    __syncthreads();
    for (int off = 1; off < 1024; off <<= 1) {
        unsigned v = (t + off < 1024) ? ss[t + off] : 0u;
        __syncthreads();
        ss[t] += v;
        __syncthreads();
    }
    int k = (int)((double)NBpts * (double)thp[0] / 3.21);
    if (k < 1) k = 1;
    if (k > NBpts) k = NBpts;
    unsigned run = ss[t] - sum;
    for (int i = 63; i >= 0; --i) {
        const unsigned c = h[i];
        if ((int)run < k && k <= (int)(run + c)) {
            selhi[b] = (unsigned)(t * 64 + i);
            selrk[b] = k - (int)run;
        }
        run += c;
    }
}

// ---------------------------------------------------------------------------
__global__ __launch_bounds__(256) void hist_lo_kernel(
    const unsigned* __restrict__ key,
    const unsigned* __restrict__ selhi,
    unsigned*       __restrict__ hist2,
    int NBpts, int N)
{
    const int n = blockIdx.x * 256 + threadIdx.x;
    if (n >= N) return;
    const int b = n / NBpts;
    const unsigned u = key[n];
    if ((u >> 16) == selhi[b])
        atomicAdd(&hist2[(size_t)b * 65536u + (u & 0xFFFFu)], 1u);
}

// ---------------------------------------------------------------------------
__global__ __launch_bounds__(1024) void scan_lo_kernel(
    const unsigned* __restrict__ hist2,
    const unsigned* __restrict__ selhi,
    const int*      __restrict__ selrk,
    unsigned*       __restrict__ selT,
    int*            __restrict__ selr)
{
    __shared__ unsigned ss[1024];
    const int b = blockIdx.x;
    const int t = threadIdx.x;
    const unsigned* h = hist2 + (size_t)b * 65536u + t * 64;
    unsigned sum = 0;
#pragma unroll 8
    for (int i = 0; i < 64; i++) sum += h[i];
    ss[t] = sum;
    __syncthreads();
    for (int off = 1; off < 1024; off <<= 1) {
        unsigned v = (t + off < 1024) ? ss[t + off] : 0u;
        __syncthreads();
        ss[t] += v;
        __syncthreads();
    }
    const int k = selrk[b];
    unsigned run = ss[t] - sum;
    for (int i = 63; i >= 0; --i) {
        const unsigned c = h[i];
        if ((int)run < k && k <= (int)(run + c)) {
            selT[b] = (selhi[b] << 16) | (unsigned)(t * 64 + i);
            selr[b] = k - (int)run;
        }
        run += c;
    }
}

// ---------------------------------------------------------------------------
__global__ __launch_bounds__(256) void mask_kernel(
    const unsigned* __restrict__ key,
    const unsigned* __restrict__ selT,
    int* __restrict__ mask,
    int* __restrict__ eqcnt,
    int NBpts)
{
    __shared__ int wc[4];
    const int n = blockIdx.x * 256 + threadIdx.x;
    const int b = n / NBpts;
    const unsigned u = key[n];
    const unsigned T = selT[b];
    mask[n] = (u > T) ? 1 : 0;
    const unsigned long long bal = __ballot(u == T);
    const int lane = threadIdx.x & 63;
    const int wid  = threadIdx.x >> 6;
    if (lane == 0) wc[wid] = __popcll(bal);
    __syncthreads();
    if (threadIdx.x == 0) eqcnt[blockIdx.x] = wc[0] + wc[1] + wc[2] + wc[3];
}

__global__ __launch_bounds__(512) void scan_kernel(
    const int* __restrict__ in, int* __restrict__ out,
    int n, int seg, int* __restrict__ total)
{
    __shared__ int ss[512];
    const int t = threadIdx.x;
    const int v = (t < n) ? in[t] : 0;
    ss[t] = v;
    __syncthreads();
    for (int off = 1; off < seg; off <<= 1) {
        int a = ((t & (seg - 1)) >= off) ? ss[t - off] : 0;
        __syncthreads();
        ss[t] += a;
        __syncthreads();
    }
    if (t < n) out[t] = ss[t] - v;
    if (total != nullptr && t == n - 1) total[0] = ss[t];
}

__global__ __launch_bounds__(256) void eqfinal_kernel(
    const unsigned* __restrict__ key,
    const unsigned* __restrict__ selT,
    const int*      __restrict__ selr,
    const int*      __restrict__ eqoff,
    int* __restrict__ mask,
    int* __restrict__ mcnt,
    int NBpts)
{
    __shared__ int wc[4], wm[4];
    const int n = blockIdx.x * 256 + threadIdx.x;
    const int b = n / NBpts;
    const unsigned u = key[n];
    const unsigned T = selT[b];
    const bool gt = (u > T);
    const bool eq = (u == T);
    const unsigned long long bal = __ballot(eq);
    const int lane = threadIdx.x & 63;
    const int wid  = threadIdx.x >> 6;
    if (lane == 0) wc[wid] = __popcll(bal);
    __syncthreads();
    int base = eqoff[blockIdx.x];
    for (int w = 0; w < wid; w++) base += wc[w];
    bool keep = false;
    if (eq) {
        const int g = base + __popcll(bal & ((1ull << lane) - 1ull));
        keep = (g < selr[b]);
        if (keep) mask[n] = 1;
    }
    const unsigned long long balm = __ballot(gt || keep);
    if (lane == 0) wm[wid] = __popcll(balm);
    __syncthreads();
    if (threadIdx.x == 0) mcnt[blockIdx.x] = wm[0] + wm[1] + wm[2] + wm[3];
}

__global__ __launch_bounds__(256) void emit_kernel(
    const int* __restrict__ mask,
    const int* __restrict__ moff,
    int* __restrict__ list)
{
    __shared__ int wc[4];
    const int n = blockIdx.x * 256 + threadIdx.x;
    const bool m = mask[n] != 0;
    const unsigned long long bal = __ballot(m);
    const int lane = threadIdx.x & 63;
    const int wid  = threadIdx.x >> 6;
    if (lane == 0) wc[wid] = __popcll(bal);
    __syncthreads();
    int base = moff[blockIdx.x];
    for (int w = 0; w < wid; w++) base += wc[w];
    if (m) list[base + __popcll(bal & ((1ull << lane) - 1ull))] = n;
}

// ---------------------------------------------------------------------------
__global__ __launch_bounds__(256) void scale2_kernel(
    const float4* __restrict__ x, float4* __restrict__ out, int n4)
{
    const int i = blockIdx.x * 256 + threadIdx.x;
    if (i < n4) {
        const float4 v = x[i];
        out[i] = make_float4(v.x + v.x, v.y + v.y, v.z + v.z, v.w + v.w);
    }
}

// ---------------------------------------------------------------------------
// conv2: same 128-point LDS-tile structure; points from ordered list,
// gathers gated by valid & mask. out[p] = conv + b_dw + x[p].
// ---------------------------------------------------------------------------
__global__ __launch_bounds__(256) void conv2_kernel(
    const float* __restrict__ x,
    const float* __restrict__ Wdw,
    const float* __restrict__ bdw,
    const int*   __restrict__ nbr,
    const int*   __restrict__ mask,
    const int*   __restrict__ list,
    const int*   __restrict__ cnt,
    float* __restrict__ out)
{
    __shared__ float Gs[2][128 * 32];
    const int t     = threadIdx.x;
    const int base  = blockIdx.x << 7;
    const int count = *cnt;
    if (base >= count) return;              // block-uniform early exit
    const int dgu   = __builtin_amdgcn_readfirstlane(t >> 6);
    const int pp    = t & 63;
    const int sw    = pp & 7;
    const int srow  = t >> 1;
    const int sh    = t & 1;
    const int stsw  = srow & 7;
    const int sp    = (base + srow < count) ? list[base + srow] : -1;

    float acc[2][8];
#pragma unroll
    for (int i = 0; i < 2; i++)
#pragma unroll
        for (int d = 0; d < 8; d++) acc[i][d] = 0.f;

    float4 stg[4];
    {
        const int j = (sp >= 0) ? nbr[(size_t)sp * K3] : -1;
        const bool v = (j >= 0) && (mask[j] != 0);
        if (v) {
            const float4* src = (const float4*)(x + (size_t)j * NC) + sh * 4;
#pragma unroll
            for (int m = 0; m < 4; m++) stg[m] = src[m];
        } else {
            const float4 z = make_float4(0.f, 0.f, 0.f, 0.f);
#pragma unroll
            for (int m = 0; m < 4; m++) stg[m] = z;
        }
    }

    for (int k = 0; k < K3; k++) {
        const int cur = k & 1;
        {
            float4* dst = (float4*)(Gs[cur] + srow * 32);
#pragma unroll
            for (int m = 0; m < 4; m++) dst[(4 * sh + m) ^ stsw] = stg[m];
        }
        __syncthreads();
        if (k + 1 < K3) {
            const int j = (sp >= 0) ? nbr[(size_t)sp * K3 + k + 1] : -1;
            const bool v = (j >= 0) && (mask[j] != 0);
            if (v) {
                const float4* src = (const float4*)(x + (size_t)j * NC) + sh * 4;
#pragma unroll
                for (int m = 0; m < 4; m++) stg[m] = src[m];
            } else {
                const float4 z = make_float4(0.f, 0.f, 0.f, 0.f);
#pragma unroll
                for (int m = 0; m < 4; m++) stg[m] = z;
            }
        }
        const float* __restrict__ Wk = Wdw + k * (NC * NC) + dgu * 8;
#pragma unroll
        for (int cc = 0; cc < 8; ++cc) {
            const float4 g0 = ((const float4*)(Gs[cur] + (pp     ) * 32))[cc ^ sw];
            const float4 g1 = ((const float4*)(Gs[cur] + (pp + 64) * 32))[cc ^ sw];
#pragma unroll
            for (int c4 = 0; c4 < 4; c4++) {
                const float* wr = Wk + (cc * 4 + c4) * NC;
                const float4 wa = ((const float4*)wr)[0];
                const float4 wb = ((const float4*)wr)[1];
                const float wv[8] = {wa.x, wa.y, wa.z, wa.w, wb.x, wb.y, wb.z, wb.w};
                const float gv[2] = {(&g0.x)[c4], (&g1.x)[c4]};
#pragma unroll
                for (int i = 0; i < 2; i++)
#pragma unroll
                    for (int d = 0; d < 8; d++)
                        acc[i][d] = fmaf(gv[i], wv[d], acc[i][d]);
            }
        }
        __syncthreads();
    }

#pragma unroll
    for (int i = 0; i < 2; i++) {
        const int p = pp + 64 * i;
        float4* dst = (float4*)(Gs[0] + p * 32);
        dst[(dgu * 2    ) ^ sw] = make_float4(acc[i][0], acc[i][1], acc[i][2], acc[i][3]);
        dst[(dgu * 2 + 1) ^ sw] = make_float4(acc[i][4], acc[i][5], acc[i][6], acc[i][7]);
    }
    __syncthreads();
    if (t < 128) {
        const int p = (base + t < count) ? list[base + t] : -1;
        if (p >= 0) {
            const float4* row = (const float4*)(Gs[0] + t * 32);
            const float4* xr  = (const float4*)(x + (size_t)p * NC);
            const float4* bb  = (const float4*)bdw;
            float4* orow = (float4*)(out + (size_t)p * NC);
            const int tsw = t & 7;
#pragma unroll
            for (int m = 0; m < 8; m++) {
                const float4 a  = row[m ^ tsw];
                const float4 bv = bb[m];
                const float4 xv = xr[m];
                orow[m] = make_float4((a.x + bv.x) + xv.x, (a.y + bv.y) + xv.y,
                                      (a.z + bv.z) + xv.z, (a.w + bv.w) + xv.w);
            }
        }
    }
}

// ---------------------------------------------------------------------------
extern "C" void kernel_launch(void* const* d_in, const int* in_sizes, int n_in,
                              void* d_out, int out_size, void* d_ws, size_t ws_size,
                              hipStream_t stream)
{
    const float* xF  = (const float*)d_in[0];
    const float* Wch = (const float*)d_in[1];
    const float* bch = (const float*)d_in[2];
    const float* Wdw = (const float*)d_in[3];
    const float* bdw = (const float*)d_in[4];
    const int*   nbr = (const int*)d_in[5];
    const int*   thp = (const int*)d_in[6];

    const int N = in_sizes[0] / NC;   // 131072
    const int NBpts = N / 2;          // 65536 per batch
    float* out = (float*)d_out;

    char* ws = (char*)d_ws;
    size_t off = 0;
    float*    x     = (float*)(ws + off);    off += (size_t)N * NC * sizeof(float);
    double*   s     = (double*)(ws + off);   off += (size_t)N * sizeof(double);
    double*   cn    = (double*)(ws + off);   off += (size_t)N * sizeof(double);
    unsigned* key   = (unsigned*)(ws + off); off += (size_t)N * sizeof(unsigned);
    int*      mask  = (int*)(ws + off);      off += (size_t)N * sizeof(int);
    int*      list  = (int*)(ws + off);      off += (size_t)N * sizeof(int);
    unsigned* hsum  = (unsigned*)(ws + off); off += 2u * 65536u * sizeof(unsigned);
    unsigned* hist2 = (unsigned*)(ws + off); off += 2u * 65536u * sizeof(unsigned);
    const size_t zero_bytes = 2u * 65536u * sizeof(unsigned);
    int*      cnt   = (int*)(ws + off);      off += 256;
    unsigned* selhi = (unsigned*)(ws + off); off += 256;
    int*      selrk = (int*)(ws + off);      off += 256;
    unsigned* selT  = (unsigned*)(ws + off); off += 256;
    int*      selr  = (int*)(ws + off);      off += 256;
    int*      eqcnt = (int*)(ws + off);      off += 512 * sizeof(int);
    int*      eqoff = (int*)(ws + off);      off += 512 * sizeof(int);
    int*      mcnt  = (int*)(ws + off);      off += 512 * sizeof(int);
    int*      moff  = (int*)(ws + off);      off += 512 * sizeof(int);

    const int nblk  = N / 256;  // 512 (selection kernels)
    const int cblk  = N / 128;  // 1024 (conv kernels, 128-pt tiles)

    // d_out doubles as the replica-major histogram scratch; scale2 overwrites.
    unsigned* rep = (unsigned*)d_out;

    hipMemsetAsync(rep, 0, (size_t)out_size * sizeof(float), stream);
    hipMemsetAsync(hist2, 0, zero_bytes, stream);
    conv1_kernel<<<cblk, 256, 0, stream>>>(xF, Wch, bch, nbr, x, s, cn);
    corr_hist_kernel<<<nblk, 256, 0, stream>>>(s, cn, nbr, key, rep, NBpts, N);
    reduce_rep_kernel<<<nblk, 256, 0, stream>>>(rep, hsum);
    scan_hi_kernel<<<2, 1024, 0, stream>>>(hsum, thp, selhi, selrk, NBpts);
    hist_lo_kernel<<<nblk, 256, 0, stream>>>(key, selhi, hist2, NBpts, N);
    scan_lo_kernel<<<2, 1024, 0, stream>>>(hist2, selhi, selrk, selT, selr);
    mask_kernel<<<nblk, 256, 0, stream>>>(key, selT, mask, eqcnt, NBpts);
    scan_kernel<<<1, 512, 0, stream>>>(eqcnt, eqoff, nblk, 256, nullptr);
    eqfinal_kernel<<<nblk, 256, 0, stream>>>(key, selT, selr, eqoff, mask, mcnt, NBpts);
    scan_kernel<<<1, 512, 0, stream>>>(mcnt, moff, nblk, 512, cnt);
    emit_kernel<<<nblk, 256, 0, stream>>>(mask, moff, list);
    scale2_kernel<<<(N * NC / 4) / 256, 256, 0, stream>>>((const float4*)x, (float4*)out, N * NC / 4);
    conv2_kernel<<<cblk, 256, 0, stream>>>(x, Wdw, bdw, nbr, mask, list, cnt, out);
}